// Round 7
// baseline (680.188 us; speedup 1.0000x reference)
//
#include <hip/hip_runtime.h>

typedef _Float16 f16x8 __attribute__((ext_vector_type(8)));
typedef float f32x4 __attribute__((ext_vector_type(4)));

#define Dd 256
#define Hh 1024

// ---------- prep: pack weights fragment-major for the 16-wave layout ----------
// W1P tile (w,kk,nt) = ((w*8+kk)*4+nt): lane(q*16+ln)*8+j holds
//   W1[kk*32+q*8+j][w*64+nt*16+ln]  (B-fragment for 16x16x32 MFMA).
// kk-major chunking: chunk = 4 nt-tiles at one kk => one shared A-fragment
// per chunk, 4 independent accumulators (no intra-chunk acc chain).
__global__ void pack_w1_kernel(const float* __restrict__ W1, _Float16* __restrict__ W1P) {
    int gid = blockIdx.x * 256 + threadIdx.x;       // 256*1024 elements
    int h = gid & 1023, d = gid >> 10;
    int w = h >> 6, nt = (h >> 4) & 3, ln = h & 15;
    int kk = d >> 5, q = (d >> 3) & 3, j = d & 7;
    W1P[(((w * 8 + kk) * 4 + nt) * 64 + q * 16 + ln) * 8 + j] = (_Float16)W1[d * 1024 + h];
}
// W2P tile (w,kk) = (w*32+kk): wave w owns D-cols [w*16,+16); kk in [0,32).
__global__ void pack_w2_kernel(const float* __restrict__ W2, _Float16* __restrict__ W2P) {
    int gid = blockIdx.x * 256 + threadIdx.x;       // 1024*256 elements
    int dcol = gid & 255, h = gid >> 8;
    int w = dcol >> 4, ln = dcol & 15;
    int kk = h >> 5, q = (h >> 3) & 3, j = h & 7;
    W2P[((w * 32 + kk) * 64 + q * 16 + ln) * 8 + j] = (_Float16)W2[h * 256 + dcol];
}

// ---------------- main: 64 blocks x 1024 thr (16 waves), register weight ring ----------------
// Round-4 design, executed with the codegen failure removed. Evidence chain:
//  - compute is ~0.8 us/eval (MfmaUtil ~2.7%); the 15 us/eval invariant across
//    all 8-wave schedules is weight-load latency serialization at 2 waves/SIMD.
//  - round 4 (16 waves, reg ring) was never measured: LDS was 41 KB, so the
//    allocator saw 2 blocks/CU reachable, targeted 8 waves/EU => 64-VGPR
//    budget vs ~117 demand => ring demoted to scratch (307 MB FETCH).
// Fix: LDS padded past 80 KB makes 2 blocks/CU physically impossible, so the
// only reachable occupancy is 4 waves/EU => 128-VGPR budget >= demand => no
// spill, no load-sinking. amdgpu_waves_per_eu(4,4) states it explicitly.
// Wave w owns H-cols [w*64,+64) (GEMM1) and D-cols [w*16,+16) (GEMM2); 16
// chunks x 4 KB per eval through a 4-slot register ring (64 VGPRs,
// issue-after-consume, depth 4 = 16 KB/wave, 256 KB/CU in flight). RAW =
// register dataflow (compiler's counted s_waitcnt vmcnt); WAR = HW writeback
// interlock. Barriers are raw lgkmcnt(0)+s_barrier — no vmcnt drain, weight
// prefetch (incl. cross-eval wraparound chunks 0..3) stays in flight.
// Accumulation order per output column (kk ascending) matches all previous
// passing kernels => identical numerics (round 4 passed, absmax 0.03125).
__global__ __launch_bounds__(1024, 4) __attribute__((amdgpu_waves_per_eu(4, 4)))
void ode_kernel(
    const float* __restrict__ z0, const float* __restrict__ tv,
    const float* __restrict__ b1, const float* __restrict__ b2,
    const _Float16* __restrict__ W1P, const _Float16* __restrict__ W2P,
    float* __restrict__ out) {
    __shared__ _Float16 act_lds[16][1032];   // 33 KB (+8 pad)
    __shared__ _Float16 z_lds[16][264];      // 8.25 KB
    __shared__ float lds_pad[10368];         // +41.5 KB => ~83 KB total: blocks 2/CU

    const int tid  = threadIdx.x;
    const int w    = tid >> 6;               // 0..15
    const int lane = tid & 63;
    const int ln   = lane & 15;
    const int q    = lane >> 4;
    const int m0   = blockIdx.x * 16;

    const float h = (tv[1] - tv[0]) * 0.125f;
    // never-true runtime-guarded touch keeps lds_pad allocated
    if (tv[0] > 1.0e30f) lds_pad[tid] = h;

    float bb1[4];
#pragma unroll
    for (int nt = 0; nt < 4; ++nt) bb1[nt] = b1[w * 64 + nt * 16 + ln];
    const float bb2 = b2[w * 16 + ln];

    const _Float16* W1w = W1P + (size_t)w * 16384;   // 32 KB: tiles (kk,nt)
    const _Float16* W2w = W2P + (size_t)w * 16384;   // 32 KB: tiles (kk)

    // 4-slot register ring: 4 x 4 x f16x8 = 64 VGPRs. Global chunk g in
    // [0,16): g<8 => W1 chunk g (kk=g, nt 0..3); g>=8 => W2 chunk g-8
    // (kk = (g-8)*4 .. +3). Slot g&3; issue-after-consume, depth 4
    // (16 KB/wave in flight; 16 waves => 256 KB/CU). 16 % 4 == 0 keeps slot
    // assignment eval-invariant across the backedge.
    f16x8 wb[4][4];

#define ISSUE(gg) { const int cm = (gg) & 15;                                        \
    const _Float16* gsrc = (cm < 8) ? (W1w + cm * 2048) : (W2w + (cm - 8) * 2048);   \
    _Pragma("unroll")                                                                \
    for (int ii = 0; ii < 4; ++ii)                                                   \
        wb[(gg) & 3][ii] = *(const f16x8*)(gsrc + ii * 512 + lane * 8);              \
    __builtin_amdgcn_sched_barrier(0); }

// act/z are LDS-only: lgkmcnt(0) publishes ds_writes, s_barrier syncs waves.
// Deliberately NO vmcnt drain — weight prefetch loads stay in flight.
#define BARRIER() asm volatile("s_waitcnt lgkmcnt(0)\n\ts_barrier" ::: "memory")

    // RK4 state (C-layout): z[r] = z[m0+q*4+r][w*16+ln]
    f32x4 z, zsum;
#pragma unroll
    for (int r = 0; r < 4; ++r)
        z[r] = z0[(m0 + q * 4 + r) * Dd + w * 16 + ln];
#pragma unroll
    for (int r = 0; r < 4; ++r)
        z_lds[q * 4 + r][w * 16 + ln] = (_Float16)z[r];
    __syncthreads();   // full drain once; prologue prefetch issued after it

    ISSUE(0); ISSUE(1); ISSUE(2); ISSUE(3);

#pragma unroll 1
    for (int ev = 0; ev < 32; ++ev) {
        const int e = ev & 3;

        // ---- GEMM1: act[:, w*64..+64) = tanh(z @ W1 + b1) ----
        f32x4 acc[4] = {{0.f,0.f,0.f,0.f},{0.f,0.f,0.f,0.f},
                        {0.f,0.f,0.f,0.f},{0.f,0.f,0.f,0.f}};
#pragma unroll
        for (int g = 0; g < 8; ++g) {        // chunk g: kk=g, one shared A-frag
            f16x8 a1 = *(const f16x8*)&z_lds[ln][g * 32 + q * 8];
#pragma unroll
            for (int nt = 0; nt < 4; ++nt)   // 4 independent acc chains
                acc[nt] = __builtin_amdgcn_mfma_f32_16x16x32_f16(
                    a1, wb[g & 3][nt], acc[nt], 0, 0, 0);
            ISSUE(g + 4);                    // g=4..7 issue W2 chunks 8..11
        }
#pragma unroll
        for (int nt = 0; nt < 4; ++nt)
#pragma unroll
            for (int r = 0; r < 4; ++r) {
                float x = acc[nt][r] + bb1[nt];
                float ex = __expf(2.0f * x);
                act_lds[q * 4 + r][w * 64 + nt * 16 + ln] =
                    (_Float16)(1.0f - 2.0f / (ex + 1.0f));
            }
        BARRIER();   // act visible; W2 chunks 8..11 remain in flight

        // ---- GEMM2: k[:, w*16..+16) = act @ W2 + b2 ----
        f32x4 acc2 = {0.f, 0.f, 0.f, 0.f};
#pragma unroll
        for (int g = 8; g < 16; ++g) {       // chunk g: kk = (g-8)*4 .. +3
#pragma unroll
            for (int i = 0; i < 4; ++i) {
                const int kk = (g - 8) * 4 + i;
                f16x8 a2 = *(const f16x8*)&act_lds[ln][kk * 32 + q * 8];
                acc2 = __builtin_amdgcn_mfma_f32_16x16x32_f16(
                    a2, wb[g & 3][i], acc2, 0, 0, 0);
            }
            ISSUE(g + 4);                    // g=12..15 wrap: next eval chunks 0..3
        }

        // ---- RK4 epilogue (registers) ----
        f32x4 kv, za;
#pragma unroll
        for (int r = 0; r < 4; ++r) kv[r] = acc2[r] + bb2;
        if (e == 0) {
            zsum = kv;
        } else if (e == 3) {
#pragma unroll
            for (int r = 0; r < 4; ++r) zsum[r] += kv[r];
        } else {
#pragma unroll
            for (int r = 0; r < 4; ++r) zsum[r] += 2.0f * kv[r];
        }
        if (e < 3) {
            const float c = (e == 2) ? h : 0.5f * h;
#pragma unroll
            for (int r = 0; r < 4; ++r) za[r] = z[r] + c * kv[r];
        } else {
#pragma unroll
            for (int r = 0; r < 4; ++r) {
                z[r] += (h * (1.0f / 6.0f)) * zsum[r];
                za[r] = z[r];
            }
        }
#pragma unroll
        for (int r = 0; r < 4; ++r)
            z_lds[q * 4 + r][w * 16 + ln] = (_Float16)za[r];
        BARRIER();   // z visible for next eval; wraparound prefetch in flight
    }

#pragma unroll
    for (int r = 0; r < 4; ++r)
        out[(m0 + q * 4 + r) * Dd + w * 16 + ln] = z[r];
#undef ISSUE
#undef BARRIER
}

extern "C" void kernel_launch(void* const* d_in, const int* in_sizes, int n_in,
                              void* d_out, int out_size, void* d_ws, size_t ws_size,
                              hipStream_t stream) {
    const float* z0 = (const float*)d_in[0];
    const float* tv = (const float*)d_in[1];
    const float* W1 = (const float*)d_in[2];   // [256][1024]
    const float* b1 = (const float*)d_in[3];   // [1024]
    const float* W2 = (const float*)d_in[4];   // [1024][256]
    const float* b2 = (const float*)d_in[5];   // [256]
    float* out = (float*)d_out;

    _Float16* W1P = (_Float16*)d_ws;           // 512 KB fragment-major
    _Float16* W2P = W1P + Hh * Dd;             // 512 KB fragment-major

    pack_w1_kernel<<<1024, 256, 0, stream>>>(W1, W1P);
    pack_w2_kernel<<<1024, 256, 0, stream>>>(W2, W2P);

    ode_kernel<<<64, 1024, 0, stream>>>(z0, tv, b1, b2, W1P, W2P, out);
}

// Round 8
// 524.199 us; speedup vs baseline: 1.2976x; 1.2976x over previous
//
#include <hip/hip_runtime.h>

typedef _Float16 f16x8 __attribute__((ext_vector_type(8)));
typedef float f32x4 __attribute__((ext_vector_type(4)));

#define Dd 256
#define Hh 1024

// ---------- prep: pack weights fragment-major ----------
// W1P tile (w,nt,kk) = ((w*8+nt)*8+kk): lane(q*16+ln)*8+j holds
//   W1[kk*32+q*8+j][w*128+nt*16+ln]  (B-fragment for 16x16x32 MFMA)
__global__ void pack_w1_kernel(const float* __restrict__ W1, _Float16* __restrict__ W1P) {
    int gid = blockIdx.x * 256 + threadIdx.x;       // 256*1024 elements
    int h = gid & 1023, d = gid >> 10;
    int w = h >> 7, nt = (h >> 4) & 7, ln = h & 15;
    int kk = d >> 5, q = (d >> 3) & 3, j = d & 7;
    W1P[(((w * 8 + nt) * 8 + kk) * 64 + q * 16 + ln) * 8 + j] = (_Float16)W1[d * 1024 + h];
}
// W2P tile (w,kk,t) = ((w*32+kk)*2+t): consumption-linear for GEMM2
__global__ void pack_w2_kernel(const float* __restrict__ W2, _Float16* __restrict__ W2P) {
    int gid = blockIdx.x * 256 + threadIdx.x;       // 1024*256 elements
    int dcol = gid & 255, h = gid >> 8;
    int w = dcol >> 5, t = (dcol >> 4) & 1, ln = dcol & 15;
    int kk = h >> 5, q = (h >> 3) & 3, j = h & 7;
    W2P[(((w * 32 + kk) * 2 + t) * 64 + q * 16 + ln) * 8 + j] = (_Float16)W2[h * 256 + dcol];
}

// ---------------- main: 64 blocks x 512 thr, SPILL-FREE 4-slot register ring ----------------
// Session-wide audit: every prior round — including the 552 us baseline —
// carried ~11-21 MB/dispatch of in-loop scratch stores (WRITE_SIZE minus the
// 1 MB `out`). A spill reload is a VMEM op, and s_waitcnt vmcnt(N) waits on
// the OLDEST (outstanding-N) ops, so any wait for a reload == vmcnt(0) ==
// full drain of the weight-prefetch queue. Every ring design therefore ran at
// effective depth ~1: 32 chunks x ~1100 cyc (one L2 round-trip each) = 15
// us/eval, the invariant we kept measuring. The spill source is the a1[8]
// fragment cache (32 VGPRs, demand ~150 vs the 128 budget at 512 thr).
// Fix: drop the cache; re-read each A-fragment from z_lds at its use
// (4 ds_read_b128 per chunk ~= 670 cyc/eval — noise). Demand ~120 < 128 =>
// zero in-loop scratch => counted vmcnt runs the ring at true depth 4
// (16 KB/wave, 128 KB/CU in flight).
// Wave w owns H-slice [w*128,+128) (GEMM1) and D-slice [w*32,+32) (GEMM2);
// 32 chunks x 4 KB per eval. RAW = register dataflow (compiler counted
// vmcnt); WAR = HW writeback interlock. sched_barrier(0) after each ISSUE
// pins issue position. Barriers are raw lgkmcnt(0)+s_barrier — no vmcnt
// drain, wraparound prefetch of next eval's chunks 0..3 stays in flight.
// Accumulation order per output column (kk ascending) unchanged => numerics
// identical to all passing rounds (absmax 0.03125).
__global__ __launch_bounds__(512, 2) void ode_kernel(
    const float* __restrict__ z0, const float* __restrict__ tv,
    const float* __restrict__ b1, const float* __restrict__ b2,
    const _Float16* __restrict__ W1P, const _Float16* __restrict__ W2P,
    float* __restrict__ out) {
    __shared__ _Float16 act_lds[16][1032];   // 33 KB (+8 pad)
    __shared__ _Float16 z_lds[16][264];      // 8.25 KB

    const int tid  = threadIdx.x;
    const int w    = tid >> 6;
    const int lane = tid & 63;
    const int ln   = lane & 15;
    const int q    = lane >> 4;
    const int m0   = blockIdx.x * 16;

    const float h = (tv[1] - tv[0]) * 0.125f;

    float bb1[8];
#pragma unroll
    for (int nt = 0; nt < 8; ++nt) bb1[nt] = b1[w * 128 + nt * 16 + ln];
    float bb2v[2];
#pragma unroll
    for (int t = 0; t < 2; ++t) bb2v[t] = b2[w * 32 + t * 16 + ln];

    const _Float16* W1w = W1P + (size_t)(w * 64) * 512;   // 64 KB: tiles (nt,kk)
    const _Float16* W2w = W2P + (size_t)(w * 64) * 512;   // 64 KB: tiles (kk,t)

    // 4-slot register ring: 4 x 4 x f16x8 = 64 VGPRs. Chunk cc (mod 32) ->
    // slot cc&3. Issue-after-consume: while chunk c is consumed, c+1..c+3 are
    // in flight; ISSUE(c+4) refills the slot just consumed. 32 % 4 == 0 keeps
    // slot assignment eval-invariant across the backedge.
    f16x8 wb[4][4];

#define ISSUE(cc) { const int cm = (cc) & 31;                                        \
    const _Float16* gsrc = (cm < 16) ? (W1w + cm * 2048) : (W2w + (cm - 16) * 2048); \
    _Pragma("unroll")                                                                \
    for (int ii = 0; ii < 4; ++ii)                                                   \
        wb[(cc) & 3][ii] = *(const f16x8*)(gsrc + ii * 512 + lane * 8);              \
    __builtin_amdgcn_sched_barrier(0); }

// act/z are LDS-only: lgkmcnt(0) publishes ds_writes, s_barrier syncs waves.
// Deliberately NO vmcnt drain — weight prefetch loads stay in flight.
#define BARRIER() asm volatile("s_waitcnt lgkmcnt(0)\n\ts_barrier" ::: "memory")

    // RK4 state (C-layout): z[t][r] = z[m0+q*4+r][w*32+t*16+ln]
    f32x4 z[2], zsum[2];
#pragma unroll
    for (int t = 0; t < 2; ++t)
#pragma unroll
        for (int r = 0; r < 4; ++r)
            z[t][r] = z0[(m0 + q * 4 + r) * Dd + w * 32 + t * 16 + ln];
#pragma unroll
    for (int t = 0; t < 2; ++t)
#pragma unroll
        for (int r = 0; r < 4; ++r)
            z_lds[q * 4 + r][w * 32 + t * 16 + ln] = (_Float16)z[t][r];
    __syncthreads();   // full drain once; prologue prefetch issued after it

    ISSUE(0); ISSUE(1); ISSUE(2); ISSUE(3);

#pragma unroll 1
    for (int ev = 0; ev < 32; ++ev) {
        const int e = ev & 3;

        // ---- GEMM1: act[:, w*128..+128) = tanh(z @ W1 + b1) ----
        // A-fragments re-read from z_lds at each use (no register cache:
        // that cache was the ~150>128 VGPR spill source poisoning vmcnt).
#pragma unroll
        for (int nt = 0; nt < 8; ++nt) {
            f32x4 acc = {0.f, 0.f, 0.f, 0.f};
#pragma unroll
            for (int half = 0; half < 2; ++half) {
                const int c = nt * 2 + half;      // chunk: tiles kk = half*4..+3
#pragma unroll
                for (int i = 0; i < 4; ++i) {
                    f16x8 a1 = *(const f16x8*)&z_lds[ln][(half * 4 + i) * 32 + q * 8];
                    acc = __builtin_amdgcn_mfma_f32_16x16x32_f16(
                        a1, wb[c & 3][i], acc, 0, 0, 0);
                }
                ISSUE(c + 4);                     // c=12..15 issue W2 chunks 16..19
            }
#pragma unroll
            for (int r = 0; r < 4; ++r) {
                float x = acc[r] + bb1[nt];
                float ex = __expf(2.0f * x);
                act_lds[q * 4 + r][w * 128 + nt * 16 + ln] =
                    (_Float16)(1.0f - 2.0f / (ex + 1.0f));
            }
        }
        BARRIER();   // act visible; W2 chunks 16..19 remain in flight

        // ---- GEMM2: k[:, w*32..+32) = act @ W2 + b2 ----
        f32x4 acc2[2] = {{0.f, 0.f, 0.f, 0.f}, {0.f, 0.f, 0.f, 0.f}};
#pragma unroll
        for (int cp = 0; cp < 16; ++cp) {
            const int c = 16 + cp;               // chunk: kk pair {2cp,2cp+1} x t{0,1}
#pragma unroll
            for (int half = 0; half < 2; ++half) {
                const int kk = cp * 2 + half;
                f16x8 a2 = *(const f16x8*)&act_lds[ln][kk * 32 + q * 8];
#pragma unroll
                for (int t = 0; t < 2; ++t)
                    acc2[t] = __builtin_amdgcn_mfma_f32_16x16x32_f16(
                        a2, wb[c & 3][half * 2 + t], acc2[t], 0, 0, 0);
            }
            ISSUE(c + 4);                        // cp>=12 wraps: next eval chunks 0..3
        }

        // ---- RK4 epilogue (registers) ----
#pragma unroll
        for (int t = 0; t < 2; ++t) {
            f32x4 kv, za;
#pragma unroll
            for (int r = 0; r < 4; ++r) kv[r] = acc2[t][r] + bb2v[t];
            if (e == 0) {
                zsum[t] = kv;
            } else if (e == 3) {
#pragma unroll
                for (int r = 0; r < 4; ++r) zsum[t][r] += kv[r];
            } else {
#pragma unroll
                for (int r = 0; r < 4; ++r) zsum[t][r] += 2.0f * kv[r];
            }
            if (e < 3) {
                const float c = (e == 2) ? h : 0.5f * h;
#pragma unroll
                for (int r = 0; r < 4; ++r) za[r] = z[t][r] + c * kv[r];
            } else {
#pragma unroll
                for (int r = 0; r < 4; ++r) {
                    z[t][r] += (h * (1.0f / 6.0f)) * zsum[t][r];
                    za[r] = z[t][r];
                }
            }
#pragma unroll
            for (int r = 0; r < 4; ++r)
                z_lds[q * 4 + r][w * 32 + t * 16 + ln] = (_Float16)za[r];
        }
        BARRIER();   // z visible for next eval; wraparound prefetch in flight
    }

#pragma unroll
    for (int t = 0; t < 2; ++t)
#pragma unroll
        for (int r = 0; r < 4; ++r)
            out[(m0 + q * 4 + r) * Dd + w * 32 + t * 16 + ln] = z[t][r];
#undef ISSUE
#undef BARRIER
}

extern "C" void kernel_launch(void* const* d_in, const int* in_sizes, int n_in,
                              void* d_out, int out_size, void* d_ws, size_t ws_size,
                              hipStream_t stream) {
    const float* z0 = (const float*)d_in[0];
    const float* tv = (const float*)d_in[1];
    const float* W1 = (const float*)d_in[2];   // [256][1024]
    const float* b1 = (const float*)d_in[3];   // [1024]
    const float* W2 = (const float*)d_in[4];   // [1024][256]
    const float* b2 = (const float*)d_in[5];   // [256]
    float* out = (float*)d_out;

    _Float16* W1P = (_Float16*)d_ws;           // 512 KB fragment-major
    _Float16* W2P = W1P + Hh * Dd;             // 512 KB fragment-major

    pack_w1_kernel<<<1024, 256, 0, stream>>>(W1, W1P);
    pack_w2_kernel<<<1024, 256, 0, stream>>>(W2, W2P);

    ode_kernel<<<64, 512, 0, stream>>>(z0, tv, b1, b2, W1P, W2P, out);
}